// Round 8
// baseline (116.909 us; speedup 1.0000x reference)
//
#include <hip/hip_runtime.h>
#include <hip/hip_fp16.h>

typedef _Float16 f16x8 __attribute__((ext_vector_type(8)));
typedef _Float16 f16x4 __attribute__((ext_vector_type(4)));
typedef float f32x4 __attribute__((ext_vector_type(4)));

// Workspace layout (bytes):
//   qv     [0,       65536)   : 32x512 f32   q = query @ Wq^T
//   bfrag  [65536,   589824)  : 512x512 f16  Wk^T in MFMA-fragment-major layout
//   scores [589824,  851968)  : 32x2048 f32  pre-softmax scores
//   vpart  [851968,  1900544) : 1024x512 f16 per-(b,sc) normalized attn@keys
#define WS_QV 0
#define WS_BF 65536
#define WS_SC 589824
#define WS_VP 851968

#define GLOAD_LDS16(g, l)                                              \
  __builtin_amdgcn_global_load_lds(                                    \
      (const __attribute__((address_space(1))) void*)(g),              \
      (__attribute__((address_space(3))) void*)(l), 16, 0, 0)

// ---------------- P: qv = query@Wq^T (fp32) + prepack Wk -> fp16 fragment layout ----
__global__ __launch_bounds__(256) void prep_kernel(
    const float* __restrict__ query, const float* __restrict__ Wq,
    const float* __restrict__ Wk, float* __restrict__ qv,
    _Float16* __restrict__ bfrag) {
  const int blk = blockIdx.x, tid = threadIdx.x;
  if (blk < 64) {
    const int b = blk >> 1;
    const int h = ((blk & 1) << 8) + tid;
    const float4* qr = (const float4*)(query + (size_t)b * 512);
    const float4* wr = (const float4*)(Wq + (size_t)h * 512);
    float acc = 0.f;
#pragma unroll 8
    for (int i = 0; i < 128; ++i) {
      float4 a = qr[i], w = wr[i];
      acc += a.x * w.x + a.y * w.y + a.z * w.z + a.w * w.w;
    }
    qv[b * 512 + h] = acc;
  } else {
    // B-fragment for mfma_f32_16x16x32_f16: unit u = nt*16 + ks
    // lane l supplies B[k = 32*ks + 8*(l>>4)+e][col = 16*nt + (l&15)] = Wk[col][k]
    const int u = (blk - 64) * 4 + (tid >> 6);
    const int l = tid & 63;
    const int col = ((u >> 4) << 4) + (l & 15);
    const int k0 = ((u & 15) << 5) + ((l >> 4) << 3);
    const float4* src = (const float4*)(Wk + (size_t)col * 512 + k0);
    float4 x = src[0], y = src[1];
    f16x8 v;
    v[0] = (_Float16)x.x; v[1] = (_Float16)x.y;
    v[2] = (_Float16)x.z; v[3] = (_Float16)x.w;
    v[4] = (_Float16)y.x; v[5] = (_Float16)y.y;
    v[6] = (_Float16)y.z; v[7] = (_Float16)y.w;
    *(f16x8*)(bfrag + (size_t)u * 512 + l * 8) = v;
  }
}

// ---------------- G: scores GEMM. Grid 1024 row-tiles of 64; 512 thr / 8 waves.
// Block tile 64 rows x 512 h (full); wave (wm,wn) = 32 rows x 128 h.
// keys staged FP32 via global_load_lds (16B) into 2x16KB dbuf, swizzled via
// pre-swizzled global source; af cvt fp32->fp16 at read; bf streamed from L2.
__global__ __launch_bounds__(512) void gemm_kernel(
    const float* __restrict__ keys, const _Float16* __restrict__ bfrag,
    const float* __restrict__ qv, const float* __restrict__ w_att,
    float* __restrict__ scores) {
  __shared__ __align__(128) unsigned char lds[32768];   // 2 x (64 rows x 64 k fp32)
  __shared__ float sred[256];                           // 8 waves x 32 rows
  const int tid = threadIdx.x, w = tid >> 6, l = tid & 63;
  const int row0 = blockIdx.x * 64;
  const int b = row0 >> 11;
  const int wm = w >> 2, wn = w & 3;

  // glds staging: wave w issues 2 loads (jj=0,1); lane covers row r, 16B slot l&15
  // LDS linear dest => global source pre-swizzled by ((r&7)<<4) within 256B row.
  const int r0s = 8 * w + (l >> 4);            // + 4*jj
  const char* gb = (const char*)keys;
  // per-lane source byte offset within a row for jj=0/1:
  const int soff0 = ((l & 15) * 16) ^ (((r0s + 0) & 7) << 4);
  const int soff1 = ((l & 15) * 16) ^ (((r0s + 4) & 7) << 4);
  const size_t grow0 = (size_t)(row0 + r0s) * 2048;
  const size_t grow1 = (size_t)(row0 + r0s + 4) * 2048;

  // ---- prologue: stage tile 0
  GLOAD_LDS16(gb + grow0 + 0 * 256 + soff0, lds + (2 * w + 0) * 1024);
  GLOAD_LDS16(gb + grow1 + 0 * 256 + soff1, lds + (2 * w + 1) * 1024);
  __syncthreads();

  f32x4 acc[2][8];
#pragma unroll
  for (int mt = 0; mt < 2; ++mt)
#pragma unroll
    for (int nt = 0; nt < 8; ++nt) {
      acc[mt][nt][0] = 0.f; acc[mt][nt][1] = 0.f;
      acc[mt][nt][2] = 0.f; acc[mt][nt][3] = 0.f;
    }

  // af read addressing: row = wm*32 + mt*16 + (l&15), kbyte = KS*128 + (l>>4)*32
  const int arow = wm * 32 + (l & 15);         // + mt*16
  const int akb = (l >> 4) << 5;               // + KS*128

#pragma unroll
  for (int kt = 0; kt < 8; ++kt) {
    // ---- issue glds for tile kt+1 into other buffer
    if (kt < 7) {
      const size_t kadd = (size_t)(kt + 1) * 256;
      unsigned char* db = lds + ((kt + 1) & 1) * 16384;
      GLOAD_LDS16(gb + grow0 + kadd + soff0, db + (2 * w + 0) * 1024);
      GLOAD_LDS16(gb + grow1 + kadd + soff1, db + (2 * w + 1) * 1024);
    }

    const unsigned char* buf = lds + (kt & 1) * 16384;
#pragma unroll
    for (int ks = 0; ks < 2; ++ks) {
      const int KST = kt * 2 + ks;
      // af: fp32 from LDS (+swizzle), cvt -> f16x8
      f16x8 af[2];
#pragma unroll
      for (int mt = 0; mt < 2; ++mt) {
        const int rr = arow + mt * 16;
        const int cb = (ks * 128 + akb) ^ ((rr & 7) << 4);
        const float4 x = *(const float4*)(buf + rr * 256 + cb);
        const float4 y = *(const float4*)(buf + rr * 256 + (cb ^ 16));
        f16x8 h;
        h[0] = (_Float16)x.x; h[1] = (_Float16)x.y;
        h[2] = (_Float16)x.z; h[3] = (_Float16)x.w;
        h[4] = (_Float16)y.x; h[5] = (_Float16)y.y;
        h[6] = (_Float16)y.z; h[7] = (_Float16)y.w;
        af[mt] = h;
      }
      // bf: 8 frags for this wave's 128 h-cols
      f16x8 bf[8];
#pragma unroll
      for (int nt = 0; nt < 8; ++nt) {
        const int u = (wn * 8 + nt) * 16 + KST;
        bf[nt] = *(const f16x8*)(bfrag + (size_t)u * 512 + l * 8);
      }
#pragma unroll
      for (int mt = 0; mt < 2; ++mt)
#pragma unroll
        for (int nt = 0; nt < 8; ++nt)
          acc[mt][nt] = __builtin_amdgcn_mfma_f32_16x16x32_f16(
              af[mt], bf[nt], acc[mt][nt], 0, 0, 0);
    }
    __syncthreads();   // drains glds (vmcnt0) -> next tile ready; read done
  }

  // ---- epilogue: tanh(qv + k) * w_att, partial over this wave's 128 h
  float rs[8];
#pragma unroll
  for (int i = 0; i < 8; ++i) rs[i] = 0.f;
#pragma unroll
  for (int nt = 0; nt < 8; ++nt) {
    const int h = (wn << 7) + (nt << 4) + (l & 15);
    const float q = qv[b * 512 + h];
    const float wa = w_att[h];
#pragma unroll
    for (int mt = 0; mt < 2; ++mt)
#pragma unroll
      for (int r = 0; r < 4; ++r) {
        float x = q + acc[mt][nt][r];
        float e = __expf(x + x);
        float t = 1.f - __fdividef(2.f, e + 1.f);
        rs[mt * 4 + r] = __builtin_fmaf(t, wa, rs[mt * 4 + r]);
      }
  }
#pragma unroll
  for (int st = 1; st <= 8; st <<= 1)
#pragma unroll
    for (int i = 0; i < 8; ++i)
      rs[i] += __shfl_xor(rs[i], st, 64);

  {
    const int idx = l & 15;
    if (idx < 8) {
      float v = rs[0];
#pragma unroll
      for (int i = 1; i < 8; ++i) v = (idx == i) ? rs[i] : v;
      // local row: mt*16 + (l>>4)*4 + r
      const int rloc = ((idx >> 2) << 4) + ((l >> 4) << 2) + (idx & 3);
      sred[w * 32 + rloc] = v;
    }
  }
  __syncthreads();
  if (tid < 64) {
    const int wmq = tid >> 5, rl = tid & 31;
    float s = sred[(wmq * 4 + 0) * 32 + rl] + sred[(wmq * 4 + 1) * 32 + rl] +
              sred[(wmq * 4 + 2) * 32 + rl] + sred[(wmq * 4 + 3) * 32 + rl];
    scores[row0 + tid] = s;
  }
}

// ---------------- S: global softmax + attn + normalized V-partial ------------------
// Grid 1024 = (b, sc): softmax over full row, V over 64-row chunk.
__global__ __launch_bounds__(256) void softv_kernel(
    const float* __restrict__ keys, const float* __restrict__ scores,
    float* __restrict__ attn, _Float16* __restrict__ vpart) {
  __shared__ float pe[2048];
  __shared__ float red_mx[4], red_se[4];
  __shared__ float4 comb[128];
  const int tid = threadIdx.x;
  const int b = blockIdx.x >> 5, sc = blockIdx.x & 31;
  const float* srow = scores + (size_t)b * 2048;

  float sv[8];
  float mx = -1e30f;
#pragma unroll
  for (int i = 0; i < 8; ++i) {
    sv[i] = srow[i * 256 + tid];
    mx = fmaxf(mx, sv[i]);
  }
#pragma unroll
  for (int st = 32; st >= 1; st >>= 1) mx = fmaxf(mx, __shfl_xor(mx, st, 64));
  if ((tid & 63) == 0) red_mx[tid >> 6] = mx;
  __syncthreads();
  mx = fmaxf(fmaxf(red_mx[0], red_mx[1]), fmaxf(red_mx[2], red_mx[3]));

  float se = 0.f;
#pragma unroll
  for (int i = 0; i < 8; ++i) {
    float e = __expf(sv[i] - mx);
    pe[i * 256 + tid] = e;
    se += e;
  }
#pragma unroll
  for (int st = 32; st >= 1; st >>= 1) se += __shfl_xor(se, st, 64);
  if ((tid & 63) == 0) red_se[tid >> 6] = se;
  __syncthreads();     // pe[] complete + red_se visible
  se = red_se[0] + red_se[1] + red_se[2] + red_se[3];
  const float rinv = 1.f / se;

  if (tid < 64) {
    int s = sc * 64 + tid;
    attn[(size_t)b * 2048 + s] = pe[s] * rinv;
  }

  // V: thread (c4, rg): float4 col c4, rows rg*32..+32 of this chunk
  const int c4 = tid & 127, rg = tid >> 7;
  const float4* kb = (const float4*)(keys + ((size_t)(b * 2048 + sc * 64 + rg * 32)) * 512);
  float4 a; a.x = 0.f; a.y = 0.f; a.z = 0.f; a.w = 0.f;
#pragma unroll 4
  for (int i = 0; i < 32; ++i) {
    float p = pe[sc * 64 + rg * 32 + i];
    float4 kv = kb[(size_t)i * 128 + c4];
    a.x = __builtin_fmaf(p, kv.x, a.x);
    a.y = __builtin_fmaf(p, kv.y, a.y);
    a.z = __builtin_fmaf(p, kv.z, a.z);
    a.w = __builtin_fmaf(p, kv.w, a.w);
  }
  if (rg) comb[c4] = a;
  __syncthreads();
  if (!rg) {
    float4 o = comb[c4];
    f16x4 h;
    h[0] = (_Float16)((a.x + o.x) * rinv);
    h[1] = (_Float16)((a.y + o.y) * rinv);
    h[2] = (_Float16)((a.z + o.z) * rinv);
    h[3] = (_Float16)((a.w + o.w) * rinv);
    *(f16x4*)(vpart + (size_t)blockIdx.x * 512 + c4 * 4) = h;
  }
}

// ---------------- R: reduce 32 chunk-partials -> out -------------------------------
__global__ __launch_bounds__(256) void reduce_kernel(
    const _Float16* __restrict__ vpart, float* __restrict__ out) {
  const int t = blockIdx.x * 256 + threadIdx.x;   // 16384 outputs
  const int b = t >> 9, d = t & 511;
  float s = 0.f;
#pragma unroll
  for (int sc = 0; sc < 32; ++sc)
    s += (float)vpart[((size_t)(b * 32 + sc)) * 512 + d];
  out[t] = s;
}

extern "C" void kernel_launch(void* const* d_in, const int* in_sizes, int n_in,
                              void* d_out, int out_size, void* d_ws, size_t ws_size,
                              hipStream_t stream) {
  const float* query = (const float*)d_in[0];
  const float* keys  = (const float*)d_in[1];
  const float* Wq    = (const float*)d_in[2];
  const float* Wk    = (const float*)d_in[3];
  const float* w_att = (const float*)d_in[4];
  float* out  = (float*)d_out;                  // [32,512]
  float* attn = out + 16384;                    // [32,2048]
  char* ws = (char*)d_ws;
  float*    qv     = (float*)(ws + WS_QV);
  _Float16* bfrag  = (_Float16*)(ws + WS_BF);
  float*    scores = (float*)(ws + WS_SC);
  _Float16* vpart  = (_Float16*)(ws + WS_VP);

  prep_kernel<<<192, 256, 0, stream>>>(query, Wq, Wk, qv, bfrag);
  gemm_kernel<<<1024, 512, 0, stream>>>(keys, bfrag, qv, w_att, scores);
  softv_kernel<<<1024, 256, 0, stream>>>(keys, scores, attn, vpart);
  reduce_kernel<<<64, 256, 0, stream>>>(vpart, out);
}